// Round 7
// baseline (227.211 us; speedup 1.0000x reference)
//
#include <hip/hip_runtime.h>
#include <stdint.h>

// Voxelization (hard), matching the JAX reference exactly.
// GRID = (1024,1024,40), VOXEL=(0.1,0.1,0.2), RANGE_LO=(-51.2,-51.2,-5.0)
// MAX_POINTS=10, MAX_VOXELS=120000.
//
// Open-addressing 64-bit hash table (2^22 slots, 33.5 MB).
// Slot = (min_point_idx << 26) | lin_voxel_id.
// Counter-driven changes (vs the round-4 measured kernel):
//  * k1: CAS-first insert — empty path (80% of points) is ONE atomic
//    round-trip instead of read+CAS; match path is CAS + fire-and-forget
//    atomicMin (monotonic-skip kept).
//  * creator detection: sequential 33.5 MB table sweep scattering bits into a
//    150 KB bitmask (hot-L2 atomicOr), replacing a 1.2M-point random table
//    read. Rank scan runs on the bitmask; ranks stored in rankOf[creator_idx]
//    (no random table writes; table is read-only after k1).

#define GXD 1024
#define GYD 1024
#define GZD 40
#define GYZ (GYD * GZD)          // 40960
#define MAXV 120000
#define MAXP 10
#define CAP 16

#define HBITS 22
#define HSIZE (1u << HBITS)      // 4,194,304 slots * 8B = 33.5 MB
#define HMASK (HSIZE - 1u)
#define KEYMASK ((1ull << 26) - 1ull)
#define EMPTY64 0xFFFFFFFFFFFFFFFFull

__device__ __forceinline__ unsigned hash_lin(unsigned l) {
    return (l * 2654435761u) >> (32 - HBITS);
}

// K1: per-point voxel coord + CAS-first hash insert with min-idx semantics.
__global__ void k1_assign(const float* __restrict__ pts, int n,
                          int* __restrict__ lin_arr, int* __restrict__ slot_arr,
                          unsigned long long* __restrict__ table) {
    int i = blockIdx.x * blockDim.x + threadIdx.x;
    if (i >= n) return;
    float x = pts[(size_t)i * 5 + 0];
    float y = pts[(size_t)i * 5 + 1];
    float z = pts[(size_t)i * 5 + 2];
    // exact reference arithmetic: f32 sub, IEEE f32 div, floorf, cast
    int cx = (int)floorf((x - (-51.2f)) / 0.1f);
    int cy = (int)floorf((y - (-51.2f)) / 0.1f);
    int cz = (int)floorf((z - (-5.0f)) / 0.2f);
    bool valid = (cx >= 0) & (cx < GXD) & (cy >= 0) & (cy < GYD) & (cz >= 0) & (cz < GZD);
    if (!valid) { lin_arr[i] = -1; slot_arr[i] = -1; return; }
    unsigned l = (unsigned)(cx * GYZ + cy * GZD + cz);
    lin_arr[i] = (int)l;
    unsigned long long want = ((unsigned long long)(unsigned)i << 26) | (unsigned long long)l;
    unsigned s = hash_lin(l);
    while (true) {
        // CAS-first: one atomic round-trip resolves the empty-slot path.
        unsigned long long cur = atomicCAS(&table[s], EMPTY64, want);
        if (cur == EMPTY64) break;                       // inserted fresh
        if ((cur & KEYMASK) == (unsigned long long)l) {  // voxel exists
            // slot idx only decreases; stale reads only show LARGER idx,
            // so skipping the atomic when cur_idx < i is safe. atomicMin
            // result unused -> fire-and-forget (no wait).
            if ((cur >> 26) > (unsigned long long)(unsigned)i)
                atomicMin(&table[s], want);
            break;
        }
        s = (s + 1) & HMASK;                             // collision: probe on
    }
    slot_arr[i] = (int)s;
}

// K2s: sequential table sweep -> creator bitmask (1 bit per point index).
// Every occupied slot's (v>>26) is the final min index = that voxel's creator.
__global__ void k2s_sweep(const unsigned long long* __restrict__ table,
                          unsigned long long* __restrict__ flagMask) {
    unsigned s = blockIdx.x * blockDim.x + threadIdx.x;
    if (s >= HSIZE) return;
    unsigned long long v = table[s];
    if (v == EMPTY64) return;
    unsigned m = (unsigned)(v >> 26);                    // idx < 2^21, no tag bits
    atomicOr(&flagMask[m >> 6], 1ull << (m & 63));
}

// K2b: single-block scan over the bitmask: per-point-block exclusive creator
// offsets + total -> voxel_num. (point-block b owns flag words [4b..4b+4).)
__global__ void k2b_scan(int nb, const unsigned long long* __restrict__ flagMask,
                         int* __restrict__ blockOff,
                         float* __restrict__ voxel_num_out) {
    __shared__ int tsum[256];
    __shared__ int toff[256];
    int t = threadIdx.x;
    int chunk = (nb + 255) / 256;
    int lo = t * chunk;
    int hi = lo + chunk; if (hi > nb) hi = nb;
    int s = 0;
    for (int j = lo; j < hi; ++j) {
        const unsigned long long* wds = &flagMask[(size_t)j * 4];
        s += __popcll(wds[0]) + __popcll(wds[1]) + __popcll(wds[2]) + __popcll(wds[3]);
    }
    tsum[t] = s;
    __syncthreads();
    if (t == 0) {
        int acc = 0;
        for (int j = 0; j < 256; ++j) { int v = tsum[j]; toff[j] = acc; acc += v; }
        int vn = acc < MAXV ? acc : MAXV;
        *voxel_num_out = (float)vn;
    }
    __syncthreads();
    int off = toff[t];
    for (int j = lo; j < hi; ++j) {
        blockOff[j] = off;
        const unsigned long long* wds = &flagMask[(size_t)j * 4];
        off += __popcll(wds[0]) + __popcll(wds[1]) + __popcll(wds[2]) + __popcll(wds[3]);
    }
}

// K2c: creators compute rank from bitmask prefix; write rankOf[i] (always) and
// coors (rank < MAXV only). No table writes.
__global__ void k2c_rank(int n, const int* __restrict__ lin_arr,
                         const unsigned long long* __restrict__ flagMask,
                         const int* __restrict__ blockOff,
                         int* __restrict__ rankOf,
                         float* __restrict__ coors_out) {
    int i = blockIdx.x * blockDim.x + threadIdx.x;
    int lane = threadIdx.x & 63, w = threadIdx.x >> 6;
    unsigned long long m = flagMask[(size_t)blockIdx.x * 4 + w];
    __shared__ int ws[4];
    if (lane == 0) ws[w] = __popcll(m);
    __syncthreads();
    bool first = (i < n) && ((m >> lane) & 1ull);
    if (!first) return;
    int off = blockOff[blockIdx.x];
    for (int j = 0; j < w; ++j) off += ws[j];
    int rank = off + (int)__popcll(m & ((1ull << lane) - 1ull));
    rankOf[i] = rank;
    if (rank >= MAXV) return;
    int l = lin_arr[i];
    int cx = l / GYZ;
    int r = l - cx * GYZ;
    int cy = r / GZD;
    int cz = r - cy * GZD;
    coors_out[(size_t)rank * 3 + 0] = (float)cx;
    coors_out[(size_t)rank * 3 + 1] = (float)cy;
    coors_out[(size_t)rank * 3 + 2] = (float)cz;
}

// K3: point -> slot -> creator idx -> rank; append own index to voxel list.
__global__ void k3_append(int n, const int* __restrict__ slot_arr,
                          const unsigned long long* __restrict__ table,
                          const int* __restrict__ rankOf,
                          int* __restrict__ vcount, int* __restrict__ vlist) {
    int i = blockIdx.x * blockDim.x + threadIdx.x;
    if (i >= n) return;
    int s = slot_arr[i];
    if (s < 0) return;
    unsigned long long v = table[s];
    int m = (int)(v >> 26);          // creator point index of this voxel
    int rank = rankOf[m];
    if (rank >= MAXV) return;
    int pos = atomicAdd(&vcount[rank], 1);
    if (pos < CAP) vlist[(size_t)rank * CAP + pos] = i;
}

// K4: per voxel: sort indices ascending (restores original-order slots), emit.
__global__ void k4_emit(const float* __restrict__ pts,
                        const int* __restrict__ vcount,
                        const int* __restrict__ vlist,
                        float* __restrict__ vox_out, float* __restrict__ num_out,
                        int* __restrict__ ovflCnt, int* __restrict__ ovflList) {
    int v = blockIdx.x * blockDim.x + threadIdx.x;
    if (v >= MAXV) return;
    int cnt = vcount[v];
    if (cnt == 0) return;
    if (cnt > CAP) {
        int e = atomicAdd(ovflCnt, 1);
        if (e < 1024) ovflList[e] = v;
        return;
    }
    int idx[CAP];
    for (int j = 0; j < cnt; ++j) idx[j] = vlist[(size_t)v * CAP + j];
    for (int a = 1; a < cnt; ++a) {
        int key = idx[a];
        int b = a - 1;
        while (b >= 0 && idx[b] > key) { idx[b + 1] = idx[b]; --b; }
        idx[b + 1] = key;
    }
    int np = cnt < MAXP ? cnt : MAXP;
    num_out[v] = (float)np;
    for (int s = 0; s < np; ++s) {
        const float* p = pts + (size_t)idx[s] * 5;
        float* o = vox_out + ((size_t)v * MAXP + s) * 5;
        o[0] = p[0]; o[1] = p[1]; o[2] = p[2]; o[3] = p[3]; o[4] = p[4];
    }
}

// K5: exact fallback for >CAP-point voxels (expected empty): serial ordered rescan.
__global__ void k5_ovfl(const float* __restrict__ pts, int n,
                        const int* __restrict__ lin_arr,
                        const int* __restrict__ vcount,
                        const int* __restrict__ ovflCnt,
                        const int* __restrict__ ovflList,
                        const float* __restrict__ coors_out,
                        float* __restrict__ vox_out, float* __restrict__ num_out) {
    if (threadIdx.x != 0 || blockIdx.x != 0) return;
    int cnt = *ovflCnt;
    if (cnt > 1024) cnt = 1024;
    for (int e = 0; e < cnt; ++e) {
        int v = ovflList[e];
        int cx = (int)coors_out[(size_t)v * 3 + 0];
        int cy = (int)coors_out[(size_t)v * 3 + 1];
        int cz = (int)coors_out[(size_t)v * 3 + 2];
        int target = cx * GYZ + cy * GZD + cz;
        int found = 0;
        for (int i = 0; i < n && found < MAXP; ++i) {
            if (lin_arr[i] == target) {
                const float* p = pts + (size_t)i * 5;
                float* o = vox_out + ((size_t)v * MAXP + found) * 5;
                for (int c = 0; c < 5; ++c) o[c] = p[c];
                ++found;
            }
        }
        int np = vcount[v] < MAXP ? vcount[v] : MAXP;
        num_out[v] = (float)np;
    }
}

extern "C" void kernel_launch(void* const* d_in, const int* in_sizes, int n_in,
                              void* d_out, int out_size, void* d_ws, size_t ws_size,
                              hipStream_t stream) {
    const float* pts = (const float*)d_in[0];
    int n = in_sizes[0] / 5;
    int nb = (n + 255) / 256;

    float* out = (float*)d_out;
    float* vox_out   = out;                       // [120000][10][5] = 6,000,000
    float* coors_out = out + 6000000;             // [120000][3]     =   360,000
    float* num_out   = out + 6360000;             // [120000]        =   120,000
    float* vn_out    = out + 6480000;             // scalar

    char* w = (char*)d_ws;
    unsigned long long* table = (unsigned long long*)w;  w += (size_t)HSIZE * 8; // 33.5 MB
    int* lin_arr   = (int*)w;               w += (size_t)n * 4;
    int* slot_arr  = (int*)w;               w += (size_t)n * 4;
    int* rankOf    = (int*)w;               w += (size_t)n * 4;
    int* blockOff  = (int*)w;               w += (size_t)nb * 4;
    int* vlist     = (int*)w;               w += (size_t)MAXV * CAP * 4;
    // zeroed region (one memset): flagMask + vcount + ovflCnt
    unsigned long long* flagMask = (unsigned long long*)w; w += (size_t)nb * 4 * 8;
    int* vcount    = (int*)w;               w += (size_t)MAXV * 4;
    int* ovflCnt   = (int*)w;               w += 4;
    int* ovflList  = (int*)w;               w += 1024 * 4;
    size_t zeroBytes = (size_t)nb * 4 * 8 + (size_t)MAXV * 4 + 4;

    hipMemsetAsync(d_out, 0, (size_t)out_size * 4, stream);
    hipMemsetAsync(table, 0xFF, (size_t)HSIZE * 8, stream);   // EMPTY64 sentinels
    hipMemsetAsync(flagMask, 0, zeroBytes, stream);

    k1_assign<<<nb, 256, 0, stream>>>(pts, n, lin_arr, slot_arr, table);
    k2s_sweep<<<HSIZE / 256, 256, 0, stream>>>(table, flagMask);
    k2b_scan<<<1, 256, 0, stream>>>(nb, flagMask, blockOff, vn_out);
    k2c_rank<<<nb, 256, 0, stream>>>(n, lin_arr, flagMask, blockOff, rankOf,
                                     coors_out);
    k3_append<<<nb, 256, 0, stream>>>(n, slot_arr, table, rankOf, vcount, vlist);
    k4_emit<<<(MAXV + 255) / 256, 256, 0, stream>>>(pts, vcount, vlist, vox_out,
                                                    num_out, ovflCnt, ovflList);
    k5_ovfl<<<1, 64, 0, stream>>>(pts, n, lin_arr, vcount, ovflCnt, ovflList,
                                  coors_out, vox_out, num_out);
}